// Round 15
// baseline (90.155 us; speedup 1.0000x reference)
//
#include <hip/hip_runtime.h>
#include <hip/hip_bf16.h>

typedef float f32x4 __attribute__((ext_vector_type(4)));
typedef __bf16 bf16x8 __attribute__((ext_vector_type(8)));
typedef unsigned short u16x8 __attribute__((ext_vector_type(8)));
typedef unsigned short u16x4 __attribute__((ext_vector_type(4)));
typedef unsigned u32x4 __attribute__((ext_vector_type(4)));

#define NB 4
#define SL 2048
#define NH 16
#define HD 64
#define KBLK 64
#define PAD 72
#define NT 16            // q-tiles of 128

static __device__ __forceinline__ unsigned short f2bf(float f) {
    unsigned u = __builtin_bit_cast(unsigned, f);
    u += 0x7fffu + ((u >> 16) & 1u);
    return (unsigned short)(u >> 16);
}

static __device__ __forceinline__ unsigned pk2(float lo, float hi) {
    unsigned r;
    asm("v_cvt_pk_bf16_f32 %0, %1, %2" : "=v"(r) : "v"(lo), "v"(hi));
    return r;
}

// raw 2^x (args <= 8 here; -1e30 -> 0 as desired)
static __device__ __forceinline__ float fexp2(float x) {
    float r;
    asm("v_exp_f32 %0, %1" : "=v"(r) : "v"(x));
    return r;
}

static __device__ __forceinline__ void pl32swap(unsigned& a, unsigned& b) {
    asm("v_permlane32_swap_b32 %0, %1" : "+v"(a), "+v"(b));
}
static __device__ __forceinline__ void pl16swap(unsigned& a, unsigned& b) {
    asm("v_permlane16_swap_b32 %0, %1" : "+v"(a), "+v"(b));
}

// ---- prologue: V fp32 [b][s][h][d] -> bf16 transposed [b][h][d][s] ----
__global__ void conv_v(const float* __restrict__ Vg, unsigned short* __restrict__ Vtb) {
    __shared__ unsigned short T[64 * PAD];
    const int tid = threadIdx.x;
    const int id  = blockIdx.x;
    const int st  = id & 31;
    const int bh  = id >> 5;
    const int s0  = st * 64;
    {
        const int sl = tid >> 2, c = (tid & 3) * 16;
        const float* src = Vg + ((size_t)((bh >> 4) * SL + s0 + sl) * NH + (bh & 15)) * HD + c;
        u16x8 a, b2;
        #pragma unroll
        for (int j = 0; j < 8; ++j) { a[j] = f2bf(src[j]); b2[j] = f2bf(src[8 + j]); }
        *(u16x8*)&T[sl * PAD + c]     = a;
        *(u16x8*)&T[sl * PAD + c + 8] = b2;
    }
    __syncthreads();
    {
        const int d = tid >> 2, sc = (tid & 3) * 16;
        u16x8 o0, o1;
        #pragma unroll
        for (int j = 0; j < 8; ++j) { o0[j] = T[(sc + j) * PAD + d]; o1[j] = T[(sc + 8 + j) * PAD + d]; }
        unsigned short* dst = Vtb + ((size_t)bh * HD + d) * SL + s0 + sc;
        *(u16x8*)dst       = o0;
        *(u16x8*)(dst + 8) = o1;
    }
}

// ---- main: 4 waves/block, 64 q-rows/wave (4 fi), TWO KV tiles per barrier round ----
__global__ __launch_bounds__(256, 2)
void fattn_kernel(const float* __restrict__ Qg, const float* __restrict__ Kg,
                  const unsigned short* __restrict__ Vtb, float* __restrict__ Og)
{
    __shared__ unsigned short Klds[2][KBLK * PAD];
    __shared__ unsigned short Vlds[2][HD * PAD];

    const int tid  = threadIdx.x;
    const int w    = tid >> 6;          // 0..3
    const int lane = tid & 63;
    const int g    = lane >> 4;
    const int li   = lane & 15;

    const int bh   = blockIdx.x & 63;
    const int rawp = blockIdx.x >> 6;   // 0..7
    const int p    = (rawp < 4) ? rawp : 11 - rawp;
    const int b    = bh >> 4;
    const int h    = bh & 15;

    int qrows[4];
    qrows[0] = p * 128 + w * 16;
    qrows[1] = p * 128 + 64 + w * 16;
    qrows[2] = (NT - 1 - p) * 128 + w * 16;
    qrows[3] = (NT - 1 - p) * 128 + 64 + w * 16;
    const int tmax   = 2 * (NT - 1 - p) + 1;
    const int nround = (tmax + 1) >> 1;     // = 16 - p (tmax+1 always even)

    const float QSCALE = 0.125f * 1.44269504088896f;  // (1/sqrt64)*log2(e)
    bf16x8 qfrag[4][2];
    #pragma unroll
    for (int fi = 0; fi < 4; ++fi) {
        const int q = qrows[fi] + li;
        const float* qp = Qg + ((size_t)(b * SL + q) * NH + h) * HD + g * 8;
        #pragma unroll
        for (int c = 0; c < 2; ++c) {
            f32x4 a = *(const f32x4*)(qp + c * 32);
            f32x4 b2 = *(const f32x4*)(qp + c * 32 + 4);
            u16x8 t;
            #pragma unroll
            for (int j = 0; j < 4; ++j) { t[j] = f2bf(a[j] * QSCALE); t[4 + j] = f2bf(b2[j] * QSCALE); }
            qfrag[fi][c] = __builtin_bit_cast(bf16x8, t);
        }
    }

    float m_run[4] = {-1e30f, -1e30f, -1e30f, -1e30f};
    float l_run[4] = {0.f, 0.f, 0.f, 0.f};   // per-lane partials, reduced at epilogue
    f32x4 oacc[4][4];
    #pragma unroll
    for (int fi = 0; fi < 4; ++fi)
        #pragma unroll
        for (int d = 0; d < 4; ++d) oacc[fi][d] = f32x4{0.f, 0.f, 0.f, 0.f};

    const int srow = tid >> 2;          // 0..63
    const int scol = (tid & 3) * 16;    // 0..48
    const float* kgbase = Kg + ((size_t)b * SL * NH + h) * HD;
    const unsigned short* vbase = Vtb + (size_t)bh * HD * SL;

    // prefetch tiles 0 and 1
    f32x4 kfA[4], kfB[4];
    u16x8 vrA0, vrA1, vrB0, vrB1;
    #pragma unroll
    for (int j = 0; j < 4; ++j) {
        kfA[j] = *(const f32x4*)(kgbase + (size_t)srow * NH * HD + scol + j * 4);
        kfB[j] = *(const f32x4*)(kgbase + (size_t)(KBLK + srow) * NH * HD + scol + j * 4);
    }
    vrA0 = *(const u16x8*)(vbase + (size_t)srow * SL + scol);
    vrA1 = *(const u16x8*)(vbase + (size_t)srow * SL + scol + 8);
    vrB0 = *(const u16x8*)(vbase + (size_t)srow * SL + KBLK + scol);
    vrB1 = *(const u16x8*)(vbase + (size_t)srow * SL + KBLK + scol + 8);

    for (int rd = 0; rd < nround; ++rd) {
        __syncthreads();    // previous round's readers done
        {
            u32x4 a0 = {pk2(kfA[0][0], kfA[0][1]), pk2(kfA[0][2], kfA[0][3]),
                        pk2(kfA[1][0], kfA[1][1]), pk2(kfA[1][2], kfA[1][3])};
            u32x4 a1 = {pk2(kfA[2][0], kfA[2][1]), pk2(kfA[2][2], kfA[2][3]),
                        pk2(kfA[3][0], kfA[3][1]), pk2(kfA[3][2], kfA[3][3])};
            u32x4 b0 = {pk2(kfB[0][0], kfB[0][1]), pk2(kfB[0][2], kfB[0][3]),
                        pk2(kfB[1][0], kfB[1][1]), pk2(kfB[1][2], kfB[1][3])};
            u32x4 b1 = {pk2(kfB[2][0], kfB[2][1]), pk2(kfB[2][2], kfB[2][3]),
                        pk2(kfB[3][0], kfB[3][1]), pk2(kfB[3][2], kfB[3][3])};
            *(u16x8*)&Klds[0][srow * PAD + scol]     = __builtin_bit_cast(u16x8, a0);
            *(u16x8*)&Klds[0][srow * PAD + scol + 8] = __builtin_bit_cast(u16x8, a1);
            *(u16x8*)&Klds[1][srow * PAD + scol]     = __builtin_bit_cast(u16x8, b0);
            *(u16x8*)&Klds[1][srow * PAD + scol + 8] = __builtin_bit_cast(u16x8, b1);
            *(u16x8*)&Vlds[0][srow * PAD + scol]     = vrA0;
            *(u16x8*)&Vlds[0][srow * PAD + scol + 8] = vrA1;
            *(u16x8*)&Vlds[1][srow * PAD + scol]     = vrB0;
            *(u16x8*)&Vlds[1][srow * PAD + scol + 8] = vrB1;
        }
        if (rd + 1 < nround) {
            const int sA = (2 * rd + 2) * KBLK;
            #pragma unroll
            for (int j = 0; j < 4; ++j) {
                kfA[j] = *(const f32x4*)(kgbase + (size_t)(sA + srow) * NH * HD + scol + j * 4);
                kfB[j] = *(const f32x4*)(kgbase + (size_t)(sA + KBLK + srow) * NH * HD + scol + j * 4);
            }
            vrA0 = *(const u16x8*)(vbase + (size_t)srow * SL + sA + scol);
            vrA1 = *(const u16x8*)(vbase + (size_t)srow * SL + sA + scol + 8);
            vrB0 = *(const u16x8*)(vbase + (size_t)srow * SL + sA + KBLK + scol);
            vrB1 = *(const u16x8*)(vbase + (size_t)srow * SL + sA + KBLK + scol + 8);
        }
        __syncthreads();    // staging visible

        #pragma unroll
        for (int tt = 0; tt < 2; ++tt) {
            const int s0 = (2 * rd + tt) * KBLK;

            bool act[4];
            #pragma unroll
            for (int fi = 0; fi < 4; ++fi) act[fi] = (s0 <= qrows[fi] + 15);

            // K fragments: read once, shared across all 4 fi
            bf16x8 kfr[4][2];
            #pragma unroll
            for (int sub = 0; sub < 4; ++sub) {
                kfr[sub][0] = __builtin_bit_cast(bf16x8, *(u16x8*)&Klds[tt][(sub * 16 + li) * PAD + g * 8]);
                kfr[sub][1] = __builtin_bit_cast(bf16x8, *(u16x8*)&Klds[tt][(sub * 16 + li) * PAD + 32 + g * 8]);
            }

            bf16x8 pfr[4][2];
            #pragma unroll
            for (int fi = 0; fi < 4; ++fi) {
                if (!act[fi]) continue;
                const int qf = qrows[fi];

                // S^T = K Q^T
                f32x4 sacc[4];
                #pragma unroll
                for (int sub = 0; sub < 4; ++sub) {
                    f32x4 c = f32x4{0.f, 0.f, 0.f, 0.f};
                    c = __builtin_amdgcn_mfma_f32_16x16x32_bf16(kfr[sub][0], qfrag[fi][0], c, 0, 0, 0);
                    c = __builtin_amdgcn_mfma_f32_16x16x32_bf16(kfr[sub][1], qfrag[fi][1], c, 0, 0, 0);
                    sacc[sub] = c;
                }

                // causal mask: s > q
                if (s0 + KBLK - 1 > qf) {
                    const int q = qf + li;
                    #pragma unroll
                    for (int sub = 0; sub < 4; ++sub)
                        #pragma unroll
                        for (int r = 0; r < 4; ++r)
                            if (s0 + sub * 16 + g * 4 + r > q) sacc[sub][r] = -1e30f;
                }

                // row max: depth-4 tree + cross-lane reduce
                float a0 = fmaxf(sacc[0][0], sacc[0][1]), a1 = fmaxf(sacc[0][2], sacc[0][3]);
                float a2 = fmaxf(sacc[1][0], sacc[1][1]), a3 = fmaxf(sacc[1][2], sacc[1][3]);
                float a4 = fmaxf(sacc[2][0], sacc[2][1]), a5 = fmaxf(sacc[2][2], sacc[2][3]);
                float a6 = fmaxf(sacc[3][0], sacc[3][1]), a7 = fmaxf(sacc[3][2], sacc[3][3]);
                float b0 = fmaxf(a0, a1), b1 = fmaxf(a2, a3), b2 = fmaxf(a4, a5), b3 = fmaxf(a6, a7);
                float pmax = fmaxf(fmaxf(b0, b1), fmaxf(b2, b3));
                pmax = fmaxf(pmax, __shfl_xor(pmax, 16, 64));
                pmax = fmaxf(pmax, __shfl_xor(pmax, 32, 64));

                // defer-max (T13)
                if (!__all(pmax - m_run[fi] <= 8.0f)) {
                    const float mnew = fmaxf(m_run[fi], pmax);
                    const float alpha = fexp2(m_run[fi] - mnew);
                    m_run[fi] = mnew;
                    l_run[fi] *= alpha;
                    #pragma unroll
                    for (int d = 0; d < 4; ++d)
                        #pragma unroll
                        for (int r = 0; r < 4; ++r) oacc[fi][d][r] *= alpha;
                }

                // P = 2^(S-m); per-lane partial row-sum (tree)
                #pragma unroll
                for (int sub = 0; sub < 4; ++sub)
                    #pragma unroll
                    for (int r = 0; r < 4; ++r)
                        sacc[sub][r] = fexp2(sacc[sub][r] - m_run[fi]);
                float s0a = (sacc[0][0] + sacc[0][1]) + (sacc[0][2] + sacc[0][3]);
                float s1a = (sacc[1][0] + sacc[1][1]) + (sacc[1][2] + sacc[1][3]);
                float s2a = (sacc[2][0] + sacc[2][1]) + (sacc[2][2] + sacc[2][3]);
                float s3a = (sacc[3][0] + sacc[3][1]) + (sacc[3][2] + sacc[3][3]);
                l_run[fi] += (s0a + s1a) + (s2a + s3a);

                // in-register P exchange: pack + permlane
                unsigned X00 = pk2(sacc[0][0], sacc[0][1]);
                unsigned X01 = pk2(sacc[0][2], sacc[0][3]);
                unsigned X10 = pk2(sacc[1][0], sacc[1][1]);
                unsigned X11 = pk2(sacc[1][2], sacc[1][3]);
                unsigned X20 = pk2(sacc[2][0], sacc[2][1]);
                unsigned X21 = pk2(sacc[2][2], sacc[2][3]);
                unsigned X30 = pk2(sacc[3][0], sacc[3][1]);
                unsigned X31 = pk2(sacc[3][2], sacc[3][3]);
                pl32swap(X00, X10); pl16swap(X00, X10);
                pl32swap(X01, X11); pl16swap(X01, X11);
                pl32swap(X20, X30); pl16swap(X20, X30);
                pl32swap(X21, X31); pl16swap(X21, X31);
                u32x4 w0 = {X00, X01, X10, X11};
                u32x4 w1 = {X20, X21, X30, X31};
                pfr[fi][0] = __builtin_bit_cast(bf16x8, w0);
                pfr[fi][1] = __builtin_bit_cast(bf16x8, w1);
            }

            // PV: V-frags read once, shared across all 4 fi
            #pragma unroll
            for (int d = 0; d < 4; ++d) {
                bf16x8 vf0 = __builtin_bit_cast(bf16x8, *(u16x8*)&Vlds[tt][(d * 16 + li) * PAD + g * 8]);
                bf16x8 vf1 = __builtin_bit_cast(bf16x8, *(u16x8*)&Vlds[tt][(d * 16 + li) * PAD + 32 + g * 8]);
                #pragma unroll
                for (int fi = 0; fi < 4; ++fi) {
                    if (!act[fi]) continue;
                    oacc[fi][d] = __builtin_amdgcn_mfma_f32_16x16x32_bf16(vf0, pfr[fi][0], oacc[fi][d], 0, 0, 0);
                    oacc[fi][d] = __builtin_amdgcn_mfma_f32_16x16x32_bf16(vf1, pfr[fi][1], oacc[fi][d], 0, 0, 0);
                }
            }
        }
    }

    // epilogue: reduce l partials across the 4 g-copies once, then write
    #pragma unroll
    for (int fi = 0; fi < 4; ++fi) {
        float lt = l_run[fi];
        lt += __shfl_xor(lt, 16, 64);
        lt += __shfl_xor(lt, 32, 64);
        const float inv = 1.0f / lt;
        float* op = Og + ((size_t)(b * SL + qrows[fi] + li) * NH + h) * HD + g * 4;
        #pragma unroll
        for (int d = 0; d < 4; ++d) {
            f32x4 o = oacc[fi][d];
            #pragma unroll
            for (int r = 0; r < 4; ++r) o[r] *= inv;
            *(f32x4*)(op + d * 16) = o;
        }
    }
}

extern "C" void kernel_launch(void* const* d_in, const int* in_sizes, int n_in,
                              void* d_out, int out_size, void* d_ws, size_t ws_size,
                              hipStream_t stream) {
    const float* Qg = (const float*)d_in[0];
    const float* Kg = (const float*)d_in[1];
    const float* Vg = (const float*)d_in[2];
    float* Og = (float*)d_out;

    const size_t elems = (size_t)NB * NH * SL * HD;
    if (ws_size < elems * sizeof(unsigned short)) return;
    unsigned short* Vtb = (unsigned short*)d_ws;

    hipLaunchKernelGGL(conv_v, dim3(NB * NH * (SL / 64)), dim3(256), 0, stream, Vg, Vtb);
    hipLaunchKernelGGL(fattn_kernel, dim3(8 * 64), dim3(256), 0, stream,
                       Qg, Kg, Vtb, Og);
}

// Round 16
// 76.064 us; speedup vs baseline: 1.1852x; 1.1852x over previous
//
#include <hip/hip_runtime.h>
#include <hip/hip_bf16.h>

typedef float f32x4 __attribute__((ext_vector_type(4)));
typedef __bf16 bf16x8 __attribute__((ext_vector_type(8)));
typedef unsigned short u16x8 __attribute__((ext_vector_type(8)));
typedef unsigned short u16x4 __attribute__((ext_vector_type(4)));
typedef unsigned u32x4 __attribute__((ext_vector_type(4)));

#define NB 4
#define SL 2048
#define NH 16
#define HD 64
#define KBLK 64
#define PAD 72
#define NT 16            // q-tiles of 128

static __device__ __forceinline__ unsigned short f2bf(float f) {
    unsigned u = __builtin_bit_cast(unsigned, f);
    u += 0x7fffu + ((u >> 16) & 1u);
    return (unsigned short)(u >> 16);
}

static __device__ __forceinline__ unsigned pk2(float lo, float hi) {
    unsigned r;
    asm("v_cvt_pk_bf16_f32 %0, %1, %2" : "=v"(r) : "v"(lo), "v"(hi));
    return r;
}

// raw 2^x (args <= 8 here; -1e30 -> 0 as desired)
static __device__ __forceinline__ float fexp2(float x) {
    float r;
    asm("v_exp_f32 %0, %1" : "=v"(r) : "v"(x));
    return r;
}

static __device__ __forceinline__ void pl32swap(unsigned& a, unsigned& b) {
    asm("v_permlane32_swap_b32 %0, %1" : "+v"(a), "+v"(b));
}
static __device__ __forceinline__ void pl16swap(unsigned& a, unsigned& b) {
    asm("v_permlane16_swap_b32 %0, %1" : "+v"(a), "+v"(b));
}

// ---- prologue: V fp32 [b][s][h][d] -> bf16 transposed [b][h][d][s] ----
__global__ void conv_v(const float* __restrict__ Vg, unsigned short* __restrict__ Vtb) {
    __shared__ unsigned short T[64 * PAD];
    const int tid = threadIdx.x;
    const int id  = blockIdx.x;
    const int st  = id & 31;
    const int bh  = id >> 5;
    const int s0  = st * 64;
    {
        const int sl = tid >> 2, c = (tid & 3) * 16;
        const float* src = Vg + ((size_t)((bh >> 4) * SL + s0 + sl) * NH + (bh & 15)) * HD + c;
        u16x8 a, b2;
        #pragma unroll
        for (int j = 0; j < 8; ++j) { a[j] = f2bf(src[j]); b2[j] = f2bf(src[8 + j]); }
        *(u16x8*)&T[sl * PAD + c]     = a;
        *(u16x8*)&T[sl * PAD + c + 8] = b2;
    }
    __syncthreads();
    {
        const int d = tid >> 2, sc = (tid & 3) * 16;
        u16x8 o0, o1;
        #pragma unroll
        for (int j = 0; j < 8; ++j) { o0[j] = T[(sc + j) * PAD + d]; o1[j] = T[(sc + 8 + j) * PAD + d]; }
        unsigned short* dst = Vtb + ((size_t)bh * HD + d) * SL + s0 + sc;
        *(u16x8*)dst       = o0;
        *(u16x8*)(dst + 8) = o1;
    }
}

// ---- main: 4 waves/block, 64 q-rows/wave (4 fi), lazy global-max softmax ----
__global__ __launch_bounds__(256, 2)
void fattn_kernel(const float* __restrict__ Qg, const float* __restrict__ Kg,
                  const unsigned short* __restrict__ Vtb, float* __restrict__ Og)
{
    __shared__ unsigned short Klds[KBLK * PAD];
    __shared__ unsigned short Vlds[HD * PAD];

    const int tid  = threadIdx.x;
    const int w    = tid >> 6;          // 0..3
    const int lane = tid & 63;
    const int g    = lane >> 4;
    const int li   = lane & 15;

    const int bh   = blockIdx.x & 63;
    const int rawp = blockIdx.x >> 6;   // 0..7
    const int p    = (rawp < 4) ? rawp : 11 - rawp;
    const int b    = bh >> 4;
    const int h    = bh & 15;

    int qrows[4];
    qrows[0] = p * 128 + w * 16;
    qrows[1] = p * 128 + 64 + w * 16;
    qrows[2] = (NT - 1 - p) * 128 + w * 16;
    qrows[3] = (NT - 1 - p) * 128 + 64 + w * 16;
    const int tmax = 2 * (NT - 1 - p) + 1;

    const float QSCALE = 0.125f * 1.44269504088896f;  // (1/sqrt64)*log2(e)
    bf16x8 qfrag[4][2];
    #pragma unroll
    for (int fi = 0; fi < 4; ++fi) {
        const int q = qrows[fi] + li;
        const float* qp = Qg + ((size_t)(b * SL + q) * NH + h) * HD + g * 8;
        #pragma unroll
        for (int c = 0; c < 2; ++c) {
            f32x4 a = *(const f32x4*)(qp + c * 32);
            f32x4 b2 = *(const f32x4*)(qp + c * 32 + 4);
            u16x8 t;
            #pragma unroll
            for (int j = 0; j < 4; ++j) { t[j] = f2bf(a[j] * QSCALE); t[4 + j] = f2bf(b2[j] * QSCALE); }
            qfrag[fi][c] = __builtin_bit_cast(bf16x8, t);
        }
    }

    float m_run[4] = {-1e30f, -1e30f, -1e30f, -1e30f};
    float l_run[4] = {0.f, 0.f, 0.f, 0.f};   // per-lane partials, reduced at epilogue
    f32x4 oacc[4][4];
    #pragma unroll
    for (int fi = 0; fi < 4; ++fi)
        #pragma unroll
        for (int d = 0; d < 4; ++d) oacc[fi][d] = f32x4{0.f, 0.f, 0.f, 0.f};

    const int srow = tid >> 2;          // 0..63
    const int scol = (tid & 3) * 16;    // 0..48
    const float* kgbase = Kg + ((size_t)b * SL * NH + h) * HD;
    const unsigned short* vbase = Vtb + (size_t)bh * HD * SL;

    f32x4 kf[4];
    #pragma unroll
    for (int j = 0; j < 4; ++j)
        kf[j] = *(const f32x4*)(kgbase + (size_t)srow * NH * HD + scol + j * 4);
    u16x8 vr0 = *(const u16x8*)(vbase + (size_t)srow * SL + scol);
    u16x8 vr1 = *(const u16x8*)(vbase + (size_t)srow * SL + scol + 8);

    for (int t = 0; t <= tmax; ++t) {
        const int s0 = t * KBLK;
        __syncthreads();
        {
            u32x4 a0 = {pk2(kf[0][0], kf[0][1]), pk2(kf[0][2], kf[0][3]),
                        pk2(kf[1][0], kf[1][1]), pk2(kf[1][2], kf[1][3])};
            u32x4 a1 = {pk2(kf[2][0], kf[2][1]), pk2(kf[2][2], kf[2][3]),
                        pk2(kf[3][0], kf[3][1]), pk2(kf[3][2], kf[3][3])};
            *(u16x8*)&Klds[srow * PAD + scol]     = __builtin_bit_cast(u16x8, a0);
            *(u16x8*)&Klds[srow * PAD + scol + 8] = __builtin_bit_cast(u16x8, a1);
            *(u16x8*)&Vlds[srow * PAD + scol]     = vr0;
            *(u16x8*)&Vlds[srow * PAD + scol + 8] = vr1;
        }
        if (t < tmax) {
            const int s1 = s0 + KBLK;
            #pragma unroll
            for (int j = 0; j < 4; ++j)
                kf[j] = *(const f32x4*)(kgbase + (size_t)(s1 + srow) * NH * HD + scol + j * 4);
            vr0 = *(const u16x8*)(vbase + (size_t)srow * SL + s1 + scol);
            vr1 = *(const u16x8*)(vbase + (size_t)srow * SL + s1 + scol + 8);
        }
        __syncthreads();

        bool act[4];
        #pragma unroll
        for (int fi = 0; fi < 4; ++fi) act[fi] = (s0 <= qrows[fi] + 15);

        // K fragments: read once, shared across all 4 fi
        bf16x8 kfr[4][2];
        #pragma unroll
        for (int sub = 0; sub < 4; ++sub) {
            kfr[sub][0] = __builtin_bit_cast(bf16x8, *(u16x8*)&Klds[(sub * 16 + li) * PAD + g * 8]);
            kfr[sub][1] = __builtin_bit_cast(bf16x8, *(u16x8*)&Klds[(sub * 16 + li) * PAD + 32 + g * 8]);
        }

        bf16x8 pfr[4][2];
        #pragma unroll
        for (int fi = 0; fi < 4; ++fi) {
            if (!act[fi]) continue;
            const int qf = qrows[fi];

            // S^T = K Q^T
            f32x4 sacc[4];
            #pragma unroll
            for (int sub = 0; sub < 4; ++sub) {
                f32x4 c = f32x4{0.f, 0.f, 0.f, 0.f};
                c = __builtin_amdgcn_mfma_f32_16x16x32_bf16(kfr[sub][0], qfrag[fi][0], c, 0, 0, 0);
                c = __builtin_amdgcn_mfma_f32_16x16x32_bf16(kfr[sub][1], qfrag[fi][1], c, 0, 0, 0);
                sacc[sub] = c;
            }

            // causal mask: s > q
            if (s0 + KBLK - 1 > qf) {
                const int q = qf + li;
                #pragma unroll
                for (int sub = 0; sub < 4; ++sub)
                    #pragma unroll
                    for (int r = 0; r < 4; ++r)
                        if (s0 + sub * 16 + g * 4 + r > q) sacc[sub][r] = -1e30f;
            }

            // per-lane PARTIAL max (depth-4 tree) — no cross-lane reduce in common case
            float a0 = fmaxf(sacc[0][0], sacc[0][1]), a1 = fmaxf(sacc[0][2], sacc[0][3]);
            float a2 = fmaxf(sacc[1][0], sacc[1][1]), a3 = fmaxf(sacc[1][2], sacc[1][3]);
            float a4 = fmaxf(sacc[2][0], sacc[2][1]), a5 = fmaxf(sacc[2][2], sacc[2][3]);
            float a6 = fmaxf(sacc[3][0], sacc[3][1]), a7 = fmaxf(sacc[3][2], sacc[3][3]);
            float b0 = fmaxf(a0, a1), b1 = fmaxf(a2, a3), b2 = fmaxf(a4, a5), b3 = fmaxf(a6, a7);
            float pp = fmaxf(fmaxf(b0, b1), fmaxf(b2, b3));

            // lazy defer-max: __all over per-lane partials is the SAME predicate as
            // (global_max <= m+8); shfls run only on the rare rescale path
            if (!__all(pp - m_run[fi] <= 8.0f)) {
                float pmax = pp;
                pmax = fmaxf(pmax, __shfl_xor(pmax, 16, 64));
                pmax = fmaxf(pmax, __shfl_xor(pmax, 32, 64));
                const float mnew = fmaxf(m_run[fi], pmax);
                const float alpha = fexp2(m_run[fi] - mnew);
                m_run[fi] = mnew;
                l_run[fi] *= alpha;
                #pragma unroll
                for (int d = 0; d < 4; ++d)
                    #pragma unroll
                    for (int r = 0; r < 4; ++r) oacc[fi][d][r] *= alpha;
            }

            // P = 2^(S-m); per-lane partial row-sum (tree)
            #pragma unroll
            for (int sub = 0; sub < 4; ++sub)
                #pragma unroll
                for (int r = 0; r < 4; ++r)
                    sacc[sub][r] = fexp2(sacc[sub][r] - m_run[fi]);
            float s0a = (sacc[0][0] + sacc[0][1]) + (sacc[0][2] + sacc[0][3]);
            float s1a = (sacc[1][0] + sacc[1][1]) + (sacc[1][2] + sacc[1][3]);
            float s2a = (sacc[2][0] + sacc[2][1]) + (sacc[2][2] + sacc[2][3]);
            float s3a = (sacc[3][0] + sacc[3][1]) + (sacc[3][2] + sacc[3][3]);
            l_run[fi] += (s0a + s1a) + (s2a + s3a);

            // in-register P exchange: pack + permlane
            unsigned X00 = pk2(sacc[0][0], sacc[0][1]);
            unsigned X01 = pk2(sacc[0][2], sacc[0][3]);
            unsigned X10 = pk2(sacc[1][0], sacc[1][1]);
            unsigned X11 = pk2(sacc[1][2], sacc[1][3]);
            unsigned X20 = pk2(sacc[2][0], sacc[2][1]);
            unsigned X21 = pk2(sacc[2][2], sacc[2][3]);
            unsigned X30 = pk2(sacc[3][0], sacc[3][1]);
            unsigned X31 = pk2(sacc[3][2], sacc[3][3]);
            pl32swap(X00, X10); pl16swap(X00, X10);
            pl32swap(X01, X11); pl16swap(X01, X11);
            pl32swap(X20, X30); pl16swap(X20, X30);
            pl32swap(X21, X31); pl16swap(X21, X31);
            u32x4 w0 = {X00, X01, X10, X11};
            u32x4 w1 = {X20, X21, X30, X31};
            pfr[fi][0] = __builtin_bit_cast(bf16x8, w0);
            pfr[fi][1] = __builtin_bit_cast(bf16x8, w1);
        }

        // PV: V-frags read once, shared across all 4 fi
        #pragma unroll
        for (int d = 0; d < 4; ++d) {
            bf16x8 vf0 = __builtin_bit_cast(bf16x8, *(u16x8*)&Vlds[(d * 16 + li) * PAD + g * 8]);
            bf16x8 vf1 = __builtin_bit_cast(bf16x8, *(u16x8*)&Vlds[(d * 16 + li) * PAD + 32 + g * 8]);
            #pragma unroll
            for (int fi = 0; fi < 4; ++fi) {
                if (!act[fi]) continue;
                oacc[fi][d] = __builtin_amdgcn_mfma_f32_16x16x32_bf16(vf0, pfr[fi][0], oacc[fi][d], 0, 0, 0);
                oacc[fi][d] = __builtin_amdgcn_mfma_f32_16x16x32_bf16(vf1, pfr[fi][1], oacc[fi][d], 0, 0, 0);
            }
        }
    }

    // epilogue: reduce l partials across the 4 g-copies once, then write
    #pragma unroll
    for (int fi = 0; fi < 4; ++fi) {
        float lt = l_run[fi];
        lt += __shfl_xor(lt, 16, 64);
        lt += __shfl_xor(lt, 32, 64);
        const float inv = 1.0f / lt;
        float* op = Og + ((size_t)(b * SL + qrows[fi] + li) * NH + h) * HD + g * 4;
        #pragma unroll
        for (int d = 0; d < 4; ++d) {
            f32x4 o = oacc[fi][d];
            #pragma unroll
            for (int r = 0; r < 4; ++r) o[r] *= inv;
            *(f32x4*)(op + d * 16) = o;
        }
    }
}

extern "C" void kernel_launch(void* const* d_in, const int* in_sizes, int n_in,
                              void* d_out, int out_size, void* d_ws, size_t ws_size,
                              hipStream_t stream) {
    const float* Qg = (const float*)d_in[0];
    const float* Kg = (const float*)d_in[1];
    const float* Vg = (const float*)d_in[2];
    float* Og = (float*)d_out;

    const size_t elems = (size_t)NB * NH * SL * HD;
    if (ws_size < elems * sizeof(unsigned short)) return;
    unsigned short* Vtb = (unsigned short*)d_ws;

    hipLaunchKernelGGL(conv_v, dim3(NB * NH * (SL / 64)), dim3(256), 0, stream, Vg, Vtb);
    hipLaunchKernelGGL(fattn_kernel, dim3(8 * 64), dim3(256), 0, stream,
                       Qg, Kg, Vtb, Og);
}